// Round 4
// baseline (233.095 us; speedup 1.0000x reference)
//
#include <hip/hip_runtime.h>

#define HIDDEN 1024
#define HEADS 16
#define HD 64
#define BATCH 2
#define SEQ 2048
#define MTOT (BATCH*SEQ)

typedef _Float16 f16;
typedef _Float16 half8 __attribute__((ext_vector_type(8)));
typedef _Float16 half4v __attribute__((ext_vector_type(4)));
typedef _Float16 half2v __attribute__((ext_vector_type(2)));
typedef float floatx4 __attribute__((ext_vector_type(4)));

// async 16B global -> LDS (dest = wave-uniform base + lane*16)
__device__ __forceinline__ void cp16(f16* lds_dst, const f16* gsrc) {
    __builtin_amdgcn_global_load_lds(
        (const __attribute__((address_space(1))) unsigned int*)gsrc,
        (__attribute__((address_space(3))) unsigned int*)lds_dst,
        16, 0, 0);
}

__device__ __forceinline__ half2v pk_f16(float a, float b) {
    return __builtin_bit_cast(half2v, __builtin_amdgcn_cvt_pkrtz(a, b));
}

// raw v_exp_f32 (no denormal-guard expansion; args are log2-domain, |x| < 50)
__device__ __forceinline__ float fast_exp2(float x) {
#if __has_builtin(__builtin_amdgcn_exp2f)
    return __builtin_amdgcn_exp2f(x);
#else
    return exp2f(x);
#endif
}

// ---------------- cast x (fp32 -> fp16) ----------------
__global__ __launch_bounds__(256) void cast_x_kernel(const float* __restrict__ x,
                                                     f16* __restrict__ xh) {
    int i = (blockIdx.x * 256 + threadIdx.x) * 4;
    floatx4 v = *(const floatx4*)(x + i);
    half4v o;
    #pragma unroll
    for (int j = 0; j < 4; ++j) o[j] = (f16)v[j];
    *(half4v*)(xh + i) = o;
}

// ------------- transpose-cast W [in][out] fp32 -> Wt [out][in] fp16 -------------
__global__ void castT_kernel(const float* __restrict__ Wq, const float* __restrict__ Wk,
                             const float* __restrict__ Wv, const float* __restrict__ Wo,
                             f16* __restrict__ wt) {
    __shared__ float tile[32][33];
    int z = blockIdx.z;
    const float* W = (z == 0) ? Wq : (z == 1) ? Wk : (z == 2) ? Wv : Wo;
    int bx = blockIdx.x, by = blockIdx.y;
    int tx = threadIdx.x, ty = threadIdx.y;
    tile[ty][tx] = W[(by * 32 + ty) * HIDDEN + bx * 32 + tx];
    __syncthreads();
    wt[(size_t)z * HIDDEN * HIDDEN + (bx * 32 + ty) * HIDDEN + by * 32 + tx] =
        (f16)tile[tx][ty];
}

// ---------------- fused QKV GEMM (BK=64, global_load_lds staging) ----------------
#define BM 128
#define BN 128
#define GBK 64

__global__ __launch_bounds__(256, 3) void gemm_qkv(const f16* __restrict__ xh,
                                                   const f16* __restrict__ wt,
                                                   const float* __restrict__ bq,
                                                   const float* __restrict__ bk,
                                                   const float* __restrict__ bv,
                                                   f16* __restrict__ qo, f16* __restrict__ ko,
                                                   f16* __restrict__ vto) {
    __shared__ f16 As[BM * GBK];
    __shared__ f16 Bs[BN * GBK];
    const int m0 = blockIdx.y * BM;
    const int n0 = blockIdx.x * BN;
    const int t = threadIdx.x;
    const int lane = t & 63, w = t >> 6;
    const int wm = w >> 1, wn = w & 1;
    const int lr = lane & 15, quad = lane >> 4;
    const int lq7 = lr & 7;

    const int baseA0 = wm * 4096 + lr * 64 + ((quad ^ lq7) * 8);
    const int baseA1 = wm * 4096 + lr * 64 + (((quad + 4) ^ lq7) * 8);
    const int baseB0 = wn * 4096 + lr * 64 + ((quad ^ lq7) * 8);
    const int baseB1 = wn * 4096 + lr * 64 + (((quad + 4) ^ lq7) * 8);

    floatx4 acc[4][4];
    #pragma unroll
    for (int i = 0; i < 4; ++i)
        #pragma unroll
        for (int j = 0; j < 4; ++j)
            #pragma unroll
            for (int r = 0; r < 4; ++r) acc[i][j][r] = 0.f;

    for (int k0 = 0; k0 < HIDDEN; k0 += GBK) {
        #pragma unroll
        for (int p = 0; p < 4; ++p) {
            int s = p * 256 + t;
            int row = s >> 3, ch = (s & 7) ^ (row & 7);
            cp16(&As[s * 8], &xh[(size_t)(m0 + row) * HIDDEN + k0 + ch * 8]);
            cp16(&Bs[s * 8], &wt[(size_t)(n0 + row) * HIDDEN + k0 + ch * 8]);
        }
        __syncthreads();
        half8 af[4], bf[4];
        #pragma unroll
        for (int i = 0; i < 4; ++i) af[i] = *(half8*)(&As[baseA0 + i * 1024]);
        #pragma unroll
        for (int j = 0; j < 4; ++j) bf[j] = *(half8*)(&Bs[baseB0 + j * 1024]);
        #pragma unroll
        for (int i = 0; i < 4; ++i)
            #pragma unroll
            for (int j = 0; j < 4; ++j)
                acc[i][j] = __builtin_amdgcn_mfma_f32_16x16x32_f16(af[i], bf[j], acc[i][j], 0, 0, 0);
        #pragma unroll
        for (int i = 0; i < 4; ++i) af[i] = *(half8*)(&As[baseA1 + i * 1024]);
        #pragma unroll
        for (int j = 0; j < 4; ++j) bf[j] = *(half8*)(&Bs[baseB1 + j * 1024]);
        #pragma unroll
        for (int i = 0; i < 4; ++i)
            #pragma unroll
            for (int j = 0; j < 4; ++j)
                acc[i][j] = __builtin_amdgcn_mfma_f32_16x16x32_f16(af[i], bf[j], acc[i][j], 0, 0, 0);
        __syncthreads();
    }

    #pragma unroll
    for (int i = 0; i < 4; ++i) {
        int mbase = m0 + wm * 64 + i * 16 + quad * 4;
        #pragma unroll
        for (int j = 0; j < 4; ++j) {
            int n = n0 + wn * 64 + j * 16 + lr;
            int proj = n >> 10;
            int c = n & 1023;
            int h = c >> 6, d = c & 63;
            const float* bp = (proj == 0) ? bq : (proj == 1) ? bk : bv;
            float bias = bp[c];
            int m = mbase;
            int b = m >> 11, s = m & 2047;
            int bh = b * HEADS + h;
            if (proj == 2) {
                half4v pv;
                #pragma unroll
                for (int r = 0; r < 4; ++r) pv[r] = (f16)(acc[i][j][r] + bias);
                *(half4v*)(&vto[((size_t)bh * HD + d) * SEQ + s]) = pv;  // natural [d][s]
            } else {
                f16* dst = (proj == 0) ? qo : ko;
                #pragma unroll
                for (int r = 0; r < 4; ++r)
                    dst[((size_t)bh * SEQ + (s + r)) * HD + d] = (f16)(acc[i][j][r] + bias);
            }
        }
    }
}

// ---------------- flash attention v14: kv-split x2 for TLP ----------------
// v13 post-mortem: prefetch (v12) NULL, phase-batch (v13) only -6% -> limiter is
// dependency-serial phases with just 2 waves/SIMD (grid 512 = 2 blocks/CU).
// v14: split the 16 KV tiles across 2 blocks (grid 1024), single 32 KB LDS
// buffer, __launch_bounds__(256,4) -> 4 blocks/CU resident = 4 waves/SIMD.
// Per-CU LDS/MFMA/VALU totals unchanged (unlike q-split, which doubles LDS
// reads); only cross-wave overlap doubles. Fixed-max softmax makes partials
// exactly additive: block writes unnormalized fp32 O-partial + per-row lsum;
// attn_combine does (P0+P1)/(l0+l1). bh stays in low 5 bits of blockIdx so
// both kv-halves of a bh land on the same XCD (K/V L2-local).
__global__ __launch_bounds__(256, 4) void attn_split(const f16* __restrict__ q,
                                                     const f16* __restrict__ k,
                                                     const f16* __restrict__ vt,
                                                     float* __restrict__ P,
                                                     float* __restrict__ lsums) {
    __shared__ f16 Klds[128 * 64];   // [perm-key][d] swizzled, 16 KB
    __shared__ f16 Vlds[64 * 128];   // [d][s] swizzled, 16 KB
    const int blk = blockIdx.x;
    const int bh = blk & 31;                 // low bits -> XCD-local
    const int qt = (blk >> 5) & 15;
    const int half = blk >> 9;               // kv half: 0 or 1
    const int t = threadIdx.x;
    const int lane = t & 63, w = t >> 6;
    const int lr = lane & 15, quad = lane >> 4;
    const int lq7 = lr & 7;

    const f16* qbh = q + (size_t)bh * SEQ * HD;
    const f16* kbh = k + (size_t)bh * SEQ * HD;
    const f16* vbh = vt + (size_t)bh * HD * SEQ;

    const int qrow = qt * 128 + w * 32;

    const int base_k0 = lr * 64 + ((quad ^ lq7) * 8);
    const int base_k1 = lr * 64 + (((quad + 4) ^ lq7) * 8);
    int voff[4];
    #pragma unroll
    for (int g2 = 0; g2 < 4; ++g2)
        voff[g2] = lr * 128 + (((g2 * 4 + quad) ^ lr) * 8);

    // Q fragments pre-scaled by (1/8)*log2(e)
    half8 qf[2][2];
    #pragma unroll
    for (int g = 0; g < 2; ++g)
        #pragma unroll
        for (int ks = 0; ks < 2; ++ks) {
            half8 v = *(const half8*)(&qbh[(size_t)(qrow + g * 16 + lr) * HD + ks * 32 + quad * 8]);
            #pragma unroll
            for (int j = 0; j < 8; ++j) v[j] = (f16)((float)v[j] * 0.1803368801f);
            qf[g][ks] = v;
        }

    floatx4 oacc[2][4];
    float lsum[2] = {0.f, 0.f};
    #pragma unroll
    for (int g = 0; g < 2; ++g)
        #pragma unroll
        for (int nt4 = 0; nt4 < 4; ++nt4)
            #pragma unroll
            for (int r = 0; r < 4; ++r) oacc[g][nt4][r] = 0.f;

    const int kt0 = half * 8;
    for (int kt = kt0; kt < kt0 + 8; ++kt) {
        const f16* kbase = kbh + (size_t)kt * 128 * HD;
        const f16* vbase = vbh + (size_t)kt * 128;
        // K staging, key-permuted within 32-key groups
        #pragma unroll
        for (int p = 0; p < 4; ++p) {
            int s = p * 256 + t;
            int row = s >> 3, ch = (s & 7) ^ (row & 7);
            int wk = row & 31;
            int key = (row & ~31) | ((wk & 12) << 1) | ((wk >> 4) << 2) | (wk & 3);
            cp16(&Klds[s * 8], &kbase[(size_t)key * HD + ch * 8]);
        }
        #pragma unroll
        for (int p = 0; p < 4; ++p) {
            int s = p * 256 + t;
            int row = s >> 4, ch = (s & 15) ^ (row & 15);
            cp16(&Vlds[s * 8], &vbase[(size_t)row * SEQ + ch * 8]);
        }
        __syncthreads();

        // ---- Phase A: batch all K fragment reads ----
        half8 kf[8][2];
        #pragma unroll
        for (int t2 = 0; t2 < 8; ++t2) {
            kf[t2][0] = *(half8*)(&Klds[base_k0 + t2 * 1024]);
            kf[t2][1] = *(half8*)(&Klds[base_k1 + t2 * 1024]);
        }

        // ---- Phase B: all QK^T MFMAs ----
        floatx4 sc[8][2];
        #pragma unroll
        for (int t2 = 0; t2 < 8; ++t2) {
            #pragma unroll
            for (int g = 0; g < 2; ++g) {
                floatx4 s = {0.f, 0.f, 0.f, 0.f};
                s = __builtin_amdgcn_mfma_f32_16x16x32_f16(kf[t2][0], qf[g][0], s, 0, 0, 0);
                s = __builtin_amdgcn_mfma_f32_16x16x32_f16(kf[t2][1], qf[g][1], s, 0, 0, 0);
                sc[t2][g] = s;
            }
        }

        // ---- Phase C: all exps + packs ----
        half8 p8[4][2];
        #pragma unroll
        for (int g2 = 0; g2 < 4; ++g2) {
            #pragma unroll
            for (int g = 0; g < 2; ++g) {
                floatx4 s0 = sc[2 * g2][g], s1 = sc[2 * g2 + 1][g];
                float pa0 = fast_exp2(s0[0]), pa1 = fast_exp2(s0[1]);
                float pa2 = fast_exp2(s0[2]), pa3 = fast_exp2(s0[3]);
                float pb0 = fast_exp2(s1[0]), pb1 = fast_exp2(s1[1]);
                float pb2 = fast_exp2(s1[2]), pb3 = fast_exp2(s1[3]);
                lsum[g] += ((pa0 + pa1) + (pa2 + pa3)) + ((pb0 + pb1) + (pb2 + pb3));
                half4v pa = __builtin_shufflevector(pk_f16(pa0, pa1), pk_f16(pa2, pa3), 0, 1, 2, 3);
                half4v pb = __builtin_shufflevector(pk_f16(pb0, pb1), pk_f16(pb2, pb3), 0, 1, 2, 3);
                p8[g2][g] = __builtin_shufflevector(pa, pb, 0, 1, 2, 3, 4, 5, 6, 7);
            }
        }

        // ---- Phase D: batch all V reads, then all PV MFMAs ----
        half8 vf[4][4];
        #pragma unroll
        for (int g2 = 0; g2 < 4; ++g2)
            #pragma unroll
            for (int nt4 = 0; nt4 < 4; ++nt4)
                vf[g2][nt4] = *(half8*)(&Vlds[voff[g2] + nt4 * 2048]);
        #pragma unroll
        for (int g2 = 0; g2 < 4; ++g2)
            #pragma unroll
            for (int nt4 = 0; nt4 < 4; ++nt4) {
                oacc[0][nt4] = __builtin_amdgcn_mfma_f32_16x16x32_f16(vf[g2][nt4], p8[g2][0], oacc[0][nt4], 0, 0, 0);
                oacc[1][nt4] = __builtin_amdgcn_mfma_f32_16x16x32_f16(vf[g2][nt4], p8[g2][1], oacc[1][nt4], 0, 0, 0);
            }

        __syncthreads();   // all waves done reading LDS before next stage overwrites
    }

    // epilogue: reduce lsum over quad-copies, store unnormalized fp32 partial + lsum
    const int b = bh >> 4, h = bh & 15;
    float* Pp = P + (size_t)half * MTOT * HIDDEN;
    float* lp = lsums + (size_t)half * 32 * SEQ + (size_t)bh * SEQ;
    #pragma unroll
    for (int g = 0; g < 2; ++g) {
        float s = lsum[g];
        s += __shfl_xor(s, 16, 64);
        s += __shfl_xor(s, 32, 64);
        int row = qrow + g * 16 + lr;
        if (quad == 0) lp[row] = s;
        #pragma unroll
        for (int nt4 = 0; nt4 < 4; ++nt4) {
            *(floatx4*)(&Pp[((size_t)(b * SEQ + row)) * HIDDEN + h * HD + nt4 * 16 + quad * 4]) = oacc[g][nt4];
        }
    }
}

// combine: ctx = (P0 + P1) / (l0 + l1), fp32 -> fp16
__global__ __launch_bounds__(256) void attn_combine(const float* __restrict__ P,
                                                    const float* __restrict__ lsums,
                                                    f16* __restrict__ ctx) {
    int i = (blockIdx.x * 256 + threadIdx.x) * 4;
    int row = i >> 10;          // b*S + s
    int col = i & 1023;
    int h = col >> 6;
    int b = row >> 11, s = row & 2047;
    int bh = b * HEADS + h;
    float l = lsums[(size_t)bh * SEQ + s] + lsums[(size_t)32 * SEQ + (size_t)bh * SEQ + s];
    float inv = 1.f / l;
    floatx4 p0 = *(const floatx4*)(P + i);
    floatx4 p1 = *(const floatx4*)(P + (size_t)MTOT * HIDDEN + i);
    half4v o;
    #pragma unroll
    for (int r = 0; r < 4; ++r) o[r] = (f16)((p0[r] + p1[r]) * inv);
    *(half4v*)(ctx + i) = o;
}

// ---------------- flash attention (v13 fallback: used when workspace too small) ----------------
__global__ __launch_bounds__(256, 2) void attn_kernel(const f16* __restrict__ q,
                                                      const f16* __restrict__ k,
                                                      const f16* __restrict__ vt,
                                                      f16* __restrict__ ctx) {
    __shared__ f16 Klds[2][128 * 64];
    __shared__ f16 Vlds[2][64 * 128];
    const int blk = blockIdx.x;
    const int bh = blk & 31, qt = blk >> 5;
    const int t = threadIdx.x;
    const int lane = t & 63, w = t >> 6;
    const int lr = lane & 15, quad = lane >> 4;
    const int lq7 = lr & 7;

    const f16* qbh = q + (size_t)bh * SEQ * HD;
    const f16* kbh = k + (size_t)bh * SEQ * HD;
    const f16* vbh = vt + (size_t)bh * HD * SEQ;

    const int qrow = qt * 128 + w * 32;

    const int base_k0 = lr * 64 + ((quad ^ lq7) * 8);
    const int base_k1 = lr * 64 + (((quad + 4) ^ lq7) * 8);
    int voff[4];
    #pragma unroll
    for (int g2 = 0; g2 < 4; ++g2)
        voff[g2] = lr * 128 + (((g2 * 4 + quad) ^ lr) * 8);

    auto stage = [&](f16* Kd, f16* Vd, int kt) {
        const f16* kbase = kbh + (size_t)kt * 128 * HD;
        const f16* vbase = vbh + (size_t)kt * 128;
        #pragma unroll
        for (int p = 0; p < 4; ++p) {
            int s = p * 256 + t;
            int row = s >> 3, ch = (s & 7) ^ (row & 7);
            int wk = row & 31;
            int key = (row & ~31) | ((wk & 12) << 1) | ((wk >> 4) << 2) | (wk & 3);
            cp16(&Kd[s * 8], &kbase[(size_t)key * HD + ch * 8]);
        }
        #pragma unroll
        for (int p = 0; p < 4; ++p) {
            int s = p * 256 + t;
            int row = s >> 4, ch = (s & 15) ^ (row & 15);
            cp16(&Vd[s * 8], &vbase[(size_t)row * SEQ + ch * 8]);
        }
    };

    stage(Klds[0], Vlds[0], 0);

    half8 qf[2][2];
    #pragma unroll
    for (int g = 0; g < 2; ++g)
        #pragma unroll
        for (int ks = 0; ks < 2; ++ks) {
            half8 v = *(const half8*)(&qbh[(size_t)(qrow + g * 16 + lr) * HD + ks * 32 + quad * 8]);
            #pragma unroll
            for (int j = 0; j < 8; ++j) v[j] = (f16)((float)v[j] * 0.1803368801f);
            qf[g][ks] = v;
        }

    floatx4 oacc[2][4];
    float lsum[2] = {0.f, 0.f};
    #pragma unroll
    for (int g = 0; g < 2; ++g)
        #pragma unroll
        for (int nt4 = 0; nt4 < 4; ++nt4)
            #pragma unroll
            for (int r = 0; r < 4; ++r) oacc[g][nt4][r] = 0.f;

    asm volatile("s_waitcnt vmcnt(0)" ::: "memory");
    __builtin_amdgcn_s_barrier();
    asm volatile("" ::: "memory");

    for (int kt = 0; kt < 16; ++kt) {
        const int cur = kt & 1;
        if (kt < 15) stage(Klds[cur ^ 1], Vlds[cur ^ 1], kt + 1);
        f16* Kl = Klds[cur];
        f16* Vl = Vlds[cur];

        half8 kf[8][2];
        #pragma unroll
        for (int t2 = 0; t2 < 8; ++t2) {
            kf[t2][0] = *(half8*)(&Kl[base_k0 + t2 * 1024]);
            kf[t2][1] = *(half8*)(&Kl[base_k1 + t2 * 1024]);
        }

        floatx4 sc[8][2];
        #pragma unroll
        for (int t2 = 0; t2 < 8; ++t2) {
            #pragma unroll
            for (int g = 0; g < 2; ++g) {
                floatx4 s = {0.f, 0.f, 0.f, 0.f};
                s = __builtin_amdgcn_mfma_f32_16x16x32_f16(kf[t2][0], qf[g][0], s, 0, 0, 0);
                s = __builtin_amdgcn_mfma_f32_16x16x32_f16(kf[t2][1], qf[g][1], s, 0, 0, 0);
                sc[t2][g] = s;
            }
        }

        half8 p8[4][2];
        #pragma unroll
        for (int g2 = 0; g2 < 4; ++g2) {
            #pragma unroll
            for (int g = 0; g < 2; ++g) {
                floatx4 s0 = sc[2 * g2][g], s1 = sc[2 * g2 + 1][g];
                float pa0 = fast_exp2(s0[0]), pa1 = fast_exp2(s0[1]);
                float pa2 = fast_exp2(s0[2]), pa3 = fast_exp2(s0[3]);
                float pb0 = fast_exp2(s1[0]), pb1 = fast_exp2(s1[1]);
                float pb2 = fast_exp2(s1[2]), pb3 = fast_exp2(s1[3]);
                lsum[g] += ((pa0 + pa1) + (pa2 + pa3)) + ((pb0 + pb1) + (pb2 + pb3));
                half4v pa = __builtin_shufflevector(pk_f16(pa0, pa1), pk_f16(pa2, pa3), 0, 1, 2, 3);
                half4v pb = __builtin_shufflevector(pk_f16(pb0, pb1), pk_f16(pb2, pb3), 0, 1, 2, 3);
                p8[g2][g] = __builtin_shufflevector(pa, pb, 0, 1, 2, 3, 4, 5, 6, 7);
            }
        }

        half8 vf[4][4];
        #pragma unroll
        for (int g2 = 0; g2 < 4; ++g2)
            #pragma unroll
            for (int nt4 = 0; nt4 < 4; ++nt4)
                vf[g2][nt4] = *(half8*)(&Vl[voff[g2] + nt4 * 2048]);
        #pragma unroll
        for (int g2 = 0; g2 < 4; ++g2)
            #pragma unroll
            for (int nt4 = 0; nt4 < 4; ++nt4) {
                oacc[0][nt4] = __builtin_amdgcn_mfma_f32_16x16x32_f16(vf[g2][nt4], p8[g2][0], oacc[0][nt4], 0, 0, 0);
                oacc[1][nt4] = __builtin_amdgcn_mfma_f32_16x16x32_f16(vf[g2][nt4], p8[g2][1], oacc[1][nt4], 0, 0, 0);
            }

        asm volatile("s_waitcnt vmcnt(0)" ::: "memory");
        __builtin_amdgcn_s_barrier();
        asm volatile("" ::: "memory");
    }

    const int b = bh >> 4, h = bh & 15;
    #pragma unroll
    for (int g = 0; g < 2; ++g) {
        float s = lsum[g];
        s += __shfl_xor(s, 16, 64);
        s += __shfl_xor(s, 32, 64);
        float inv = 1.f / s;
        #pragma unroll
        for (int nt4 = 0; nt4 < 4; ++nt4) {
            half4v o4;
            #pragma unroll
            for (int r = 0; r < 4; ++r) o4[r] = (f16)(oacc[g][nt4][r] * inv);
            *(half4v*)(&ctx[((size_t)(b * SEQ + qrow + g * 16 + lr)) * HIDDEN + h * HD + nt4 * 16 + quad * 4]) = o4;
        }
    }
}

// ---------------- output projection GEMM (64x128 tiles, BK=64, fp32 out) ----------------
#define OBM 64
__global__ __launch_bounds__(256, 4) void gemm_out(const f16* __restrict__ ah,
                                                   const f16* __restrict__ wto,
                                                   const float* __restrict__ bo,
                                                   float* __restrict__ out) {
    __shared__ f16 As[OBM * GBK];   // 8 KB
    __shared__ f16 Bs[BN * GBK];    // 16 KB
    const int m0 = blockIdx.y * OBM;
    const int n0 = blockIdx.x * BN;
    const int t = threadIdx.x;
    const int lane = t & 63, w = t >> 6;
    const int wm = w >> 1, wn = w & 1;   // wave tile: 32 m x 64 n
    const int lr = lane & 15, quad = lane >> 4;
    const int lq7 = lr & 7;

    const int baseA0 = wm * 2048 + lr * 64 + ((quad ^ lq7) * 8);
    const int baseA1 = wm * 2048 + lr * 64 + (((quad + 4) ^ lq7) * 8);
    const int baseB0 = wn * 4096 + lr * 64 + ((quad ^ lq7) * 8);
    const int baseB1 = wn * 4096 + lr * 64 + (((quad + 4) ^ lq7) * 8);

    floatx4 acc[2][4];
    #pragma unroll
    for (int i = 0; i < 2; ++i)
        #pragma unroll
        for (int j = 0; j < 4; ++j)
            #pragma unroll
            for (int r = 0; r < 4; ++r) acc[i][j][r] = 0.f;

    for (int k0 = 0; k0 < HIDDEN; k0 += GBK) {
        #pragma unroll
        for (int p = 0; p < 2; ++p) {
            int s = p * 256 + t;
            int row = s >> 3, ch = (s & 7) ^ (row & 7);
            cp16(&As[s * 8], &ah[(size_t)(m0 + row) * HIDDEN + k0 + ch * 8]);
        }
        #pragma unroll
        for (int p = 0; p < 4; ++p) {
            int s = p * 256 + t;
            int row = s >> 3, ch = (s & 7) ^ (row & 7);
            cp16(&Bs[s * 8], &wto[(size_t)(n0 + row) * HIDDEN + k0 + ch * 8]);
        }
        __syncthreads();
        half8 af[2], bf[4];
        #pragma unroll
        for (int i = 0; i < 2; ++i) af[i] = *(half8*)(&As[baseA0 + i * 1024]);
        #pragma unroll
        for (int j = 0; j < 4; ++j) bf[j] = *(half8*)(&Bs[baseB0 + j * 1024]);
        #pragma unroll
        for (int i = 0; i < 2; ++i)
            #pragma unroll
            for (int j = 0; j < 4; ++j)
                acc[i][j] = __builtin_amdgcn_mfma_f32_16x16x32_f16(af[i], bf[j], acc[i][j], 0, 0, 0);
        #pragma unroll
        for (int i = 0; i < 2; ++i) af[i] = *(half8*)(&As[baseA1 + i * 1024]);
        #pragma unroll
        for (int j = 0; j < 4; ++j) bf[j] = *(half8*)(&Bs[baseB1 + j * 1024]);
        #pragma unroll
        for (int i = 0; i < 2; ++i)
            #pragma unroll
            for (int j = 0; j < 4; ++j)
                acc[i][j] = __builtin_amdgcn_mfma_f32_16x16x32_f16(af[i], bf[j], acc[i][j], 0, 0, 0);
        __syncthreads();
    }

    #pragma unroll
    for (int i = 0; i < 2; ++i) {
        int mbase = m0 + wm * 32 + i * 16 + quad * 4;
        #pragma unroll
        for (int j = 0; j < 4; ++j) {
            int n = n0 + wn * 64 + j * 16 + lr;
            float bias = bo[n];
            #pragma unroll
            for (int r = 0; r < 4; ++r)
                out[(size_t)(mbase + r) * HIDDEN + n] = acc[i][j][r] + bias;
        }
    }
}

// ---------------- launch ----------------
extern "C" void kernel_launch(void* const* d_in, const int* in_sizes, int n_in,
                              void* d_out, int out_size, void* d_ws, size_t ws_size,
                              hipStream_t stream) {
    const float* x  = (const float*)d_in[0];
    const float* Wq = (const float*)d_in[1];
    const float* bq = (const float*)d_in[2];
    const float* Wk = (const float*)d_in[3];
    const float* bk = (const float*)d_in[4];
    const float* Wv = (const float*)d_in[5];
    const float* bv = (const float*)d_in[6];
    const float* Wo = (const float*)d_in[7];
    const float* bo = (const float*)d_in[8];
    float* out = (float*)d_out;

    char* ws = (char*)d_ws;
    f16* xh   = (f16*)(ws);                   // 8 MB
    f16* wt   = (f16*)(ws + (8u  << 20));     // 8 MB
    f16* qw   = (f16*)(ws + (16u << 20));     // 8 MB
    f16* kw   = (f16*)(ws + (24u << 20));     // 8 MB
    f16* vtw  = (f16*)(ws + (32u << 20));     // 8 MB (natural [d][s] layout)
    f16* ctxh = (f16*)(ws + (40u << 20));     // 8 MB

    // kv-split workspace (beyond the base 48 MB): 32 MB fp32 partials + 0.5 MB lsums
    const size_t P_off = (size_t)48u << 20;
    const size_t L_off = P_off + (size_t)2 * MTOT * HIDDEN * sizeof(float);
    const size_t REQ   = L_off + (size_t)2 * 32 * SEQ * sizeof(float);

    cast_x_kernel<<<MTOT * HIDDEN / 1024, 256, 0, stream>>>(x, xh);
    castT_kernel<<<dim3(32, 32, 4), dim3(32, 32), 0, stream>>>(Wq, Wk, Wv, Wo, wt);
    gemm_qkv<<<dim3(3 * HIDDEN / BN, MTOT / BM), 256, 0, stream>>>(xh, wt, bq, bk, bv, qw, kw, vtw);
    if (ws_size >= REQ) {
        float* P  = (float*)(ws + P_off);
        float* ls = (float*)(ws + L_off);
        attn_split<<<2 * 32 * (SEQ / 128), 256, 0, stream>>>(qw, kw, vtw, P, ls);
        attn_combine<<<MTOT * HIDDEN / 1024, 256, 0, stream>>>(P, ls, ctxh);
    } else {
        attn_kernel<<<32 * (SEQ / 128), 256, 0, stream>>>(qw, kw, vtw, ctxh);
    }
    gemm_out<<<dim3(HIDDEN / BN, MTOT / OBM), 256, 0, stream>>>(ctxh, wt + (size_t)3 * HIDDEN * HIDDEN, bo, out);
}

// Round 5
// 181.204 us; speedup vs baseline: 1.2864x; 1.2864x over previous
//
#include <hip/hip_runtime.h>

#define HIDDEN 1024
#define HEADS 16
#define HD 64
#define BATCH 2
#define SEQ 2048
#define MTOT (BATCH*SEQ)

typedef _Float16 f16;
typedef _Float16 half8 __attribute__((ext_vector_type(8)));
typedef _Float16 half4v __attribute__((ext_vector_type(4)));
typedef _Float16 half2v __attribute__((ext_vector_type(2)));
typedef float floatx4 __attribute__((ext_vector_type(4)));

// async 16B global -> LDS (dest = wave-uniform base + lane*16)
__device__ __forceinline__ void cp16(f16* lds_dst, const f16* gsrc) {
    __builtin_amdgcn_global_load_lds(
        (const __attribute__((address_space(1))) unsigned int*)gsrc,
        (__attribute__((address_space(3))) unsigned int*)lds_dst,
        16, 0, 0);
}

__device__ __forceinline__ half2v pk_f16(float a, float b) {
    return __builtin_bit_cast(half2v, __builtin_amdgcn_cvt_pkrtz(a, b));
}

// raw v_exp_f32 (no denormal-guard expansion; args are log2-domain, |x| < 50)
__device__ __forceinline__ float fast_exp2(float x) {
#if __has_builtin(__builtin_amdgcn_exp2f)
    return __builtin_amdgcn_exp2f(x);
#else
    return exp2f(x);
#endif
}

// ---------------- cast x (fp32 -> fp16) ----------------
__global__ __launch_bounds__(256) void cast_x_kernel(const float* __restrict__ x,
                                                     f16* __restrict__ xh) {
    int i = (blockIdx.x * 256 + threadIdx.x) * 4;
    floatx4 v = *(const floatx4*)(x + i);
    half4v o;
    #pragma unroll
    for (int j = 0; j < 4; ++j) o[j] = (f16)v[j];
    *(half4v*)(xh + i) = o;
}

// ------------- transpose-cast W [in][out] fp32 -> Wt [out][in] fp16 -------------
__global__ void castT_kernel(const float* __restrict__ Wq, const float* __restrict__ Wk,
                             const float* __restrict__ Wv, const float* __restrict__ Wo,
                             f16* __restrict__ wt) {
    __shared__ float tile[32][33];
    int z = blockIdx.z;
    const float* W = (z == 0) ? Wq : (z == 1) ? Wk : (z == 2) ? Wv : Wo;
    int bx = blockIdx.x, by = blockIdx.y;
    int tx = threadIdx.x, ty = threadIdx.y;
    tile[ty][tx] = W[(by * 32 + ty) * HIDDEN + bx * 32 + tx];
    __syncthreads();
    wt[(size_t)z * HIDDEN * HIDDEN + (bx * 32 + ty) * HIDDEN + by * 32 + tx] =
        (f16)tile[tx][ty];
}

// ---------------- fused QKV GEMM (BK=64, global_load_lds staging) ----------------
#define BM 128
#define BN 128
#define GBK 64

__global__ __launch_bounds__(256, 3) void gemm_qkv(const f16* __restrict__ xh,
                                                   const f16* __restrict__ wt,
                                                   const float* __restrict__ bq,
                                                   const float* __restrict__ bk,
                                                   const float* __restrict__ bv,
                                                   f16* __restrict__ qo, f16* __restrict__ ko,
                                                   f16* __restrict__ vto) {
    __shared__ f16 As[BM * GBK];
    __shared__ f16 Bs[BN * GBK];
    const int m0 = blockIdx.y * BM;
    const int n0 = blockIdx.x * BN;
    const int t = threadIdx.x;
    const int lane = t & 63, w = t >> 6;
    const int wm = w >> 1, wn = w & 1;
    const int lr = lane & 15, quad = lane >> 4;
    const int lq7 = lr & 7;

    const int baseA0 = wm * 4096 + lr * 64 + ((quad ^ lq7) * 8);
    const int baseA1 = wm * 4096 + lr * 64 + (((quad + 4) ^ lq7) * 8);
    const int baseB0 = wn * 4096 + lr * 64 + ((quad ^ lq7) * 8);
    const int baseB1 = wn * 4096 + lr * 64 + (((quad + 4) ^ lq7) * 8);

    floatx4 acc[4][4];
    #pragma unroll
    for (int i = 0; i < 4; ++i)
        #pragma unroll
        for (int j = 0; j < 4; ++j)
            #pragma unroll
            for (int r = 0; r < 4; ++r) acc[i][j][r] = 0.f;

    for (int k0 = 0; k0 < HIDDEN; k0 += GBK) {
        #pragma unroll
        for (int p = 0; p < 4; ++p) {
            int s = p * 256 + t;
            int row = s >> 3, ch = (s & 7) ^ (row & 7);
            cp16(&As[s * 8], &xh[(size_t)(m0 + row) * HIDDEN + k0 + ch * 8]);
            cp16(&Bs[s * 8], &wt[(size_t)(n0 + row) * HIDDEN + k0 + ch * 8]);
        }
        __syncthreads();
        half8 af[4], bf[4];
        #pragma unroll
        for (int i = 0; i < 4; ++i) af[i] = *(half8*)(&As[baseA0 + i * 1024]);
        #pragma unroll
        for (int j = 0; j < 4; ++j) bf[j] = *(half8*)(&Bs[baseB0 + j * 1024]);
        #pragma unroll
        for (int i = 0; i < 4; ++i)
            #pragma unroll
            for (int j = 0; j < 4; ++j)
                acc[i][j] = __builtin_amdgcn_mfma_f32_16x16x32_f16(af[i], bf[j], acc[i][j], 0, 0, 0);
        #pragma unroll
        for (int i = 0; i < 4; ++i) af[i] = *(half8*)(&As[baseA1 + i * 1024]);
        #pragma unroll
        for (int j = 0; j < 4; ++j) bf[j] = *(half8*)(&Bs[baseB1 + j * 1024]);
        #pragma unroll
        for (int i = 0; i < 4; ++i)
            #pragma unroll
            for (int j = 0; j < 4; ++j)
                acc[i][j] = __builtin_amdgcn_mfma_f32_16x16x32_f16(af[i], bf[j], acc[i][j], 0, 0, 0);
        __syncthreads();
    }

    #pragma unroll
    for (int i = 0; i < 4; ++i) {
        int mbase = m0 + wm * 64 + i * 16 + quad * 4;
        #pragma unroll
        for (int j = 0; j < 4; ++j) {
            int n = n0 + wn * 64 + j * 16 + lr;
            int proj = n >> 10;
            int c = n & 1023;
            int h = c >> 6, d = c & 63;
            const float* bp = (proj == 0) ? bq : (proj == 1) ? bk : bv;
            float bias = bp[c];
            int m = mbase;
            int b = m >> 11, s = m & 2047;
            int bh = b * HEADS + h;
            if (proj == 2) {
                half4v pv;
                #pragma unroll
                for (int r = 0; r < 4; ++r) pv[r] = (f16)(acc[i][j][r] + bias);
                *(half4v*)(&vto[((size_t)bh * HD + d) * SEQ + s]) = pv;  // natural [d][s]
            } else {
                f16* dst = (proj == 0) ? qo : ko;
                #pragma unroll
                for (int r = 0; r < 4; ++r)
                    dst[((size_t)bh * SEQ + (s + r)) * HD + d] = (f16)(acc[i][j][r] + bias);
            }
        }
    }
}

// ---------------- flash attention v15: within-wave pipe interleave ----------------
// v14 post-mortem: kv-split delivered occupancy (36%) but fp32 partial writes
// caused 5x HBM amplification -> reverted. Cycle model: MFMA 2.5k / VALU 2.4k /
// LDS 2.6k cyc per CU per tile, serial sum = 7.5k = measured 46 us. v15 keeps
// v13's dbuf shell and builds a 1-deep software pipeline inside each tile so
// the three pipes overlap WITHIN each wave:
//   KR0 KR1 VR0 | QK0 | KR2 VR1 | QK1 | EXP0 | KR3 VR2 | QK2 | EXP1 PV0 |
//   VR3 | QK3 | EXP2 PV1 | EXP3 PV2 | PV3
// LDS reads land under MFMAs (counted lgkmcnt); EXP (VALU) sits between
// independent MFMA clusters. All pipeline state in NAMED per-stage variables
// (static indexing). lsum/oacc accumulation order unchanged -> same numerics.
#define KREAD(j) do {                                                  \
    kf##j[0][0] = *(half8*)(&Kl[base_k0 + (2*j) * 1024]);              \
    kf##j[0][1] = *(half8*)(&Kl[base_k1 + (2*j) * 1024]);              \
    kf##j[1][0] = *(half8*)(&Kl[base_k0 + (2*j+1) * 1024]);            \
    kf##j[1][1] = *(half8*)(&Kl[base_k1 + (2*j+1) * 1024]);            \
} while(0)

#define VREAD(j) do {                                                  \
    vf##j[0] = *(half8*)(&Vl[voff[j] + 0 * 2048]);                     \
    vf##j[1] = *(half8*)(&Vl[voff[j] + 1 * 2048]);                     \
    vf##j[2] = *(half8*)(&Vl[voff[j] + 2 * 2048]);                     \
    vf##j[3] = *(half8*)(&Vl[voff[j] + 3 * 2048]);                     \
} while(0)

#define QK(j) do {                                                     \
    _Pragma("unroll")                                                  \
    for (int a = 0; a < 2; ++a) {                                      \
        _Pragma("unroll")                                              \
        for (int g = 0; g < 2; ++g) {                                  \
            floatx4 s = {0.f, 0.f, 0.f, 0.f};                          \
            s = __builtin_amdgcn_mfma_f32_16x16x32_f16(kf##j[a][0], qf[g][0], s, 0, 0, 0); \
            s = __builtin_amdgcn_mfma_f32_16x16x32_f16(kf##j[a][1], qf[g][1], s, 0, 0, 0); \
            sc##j[a][g] = s;                                           \
        }                                                              \
    }                                                                  \
} while(0)

#define EXPP(j) do {                                                   \
    _Pragma("unroll")                                                  \
    for (int g = 0; g < 2; ++g) {                                      \
        floatx4 s0 = sc##j[0][g], s1 = sc##j[1][g];                    \
        float pa0 = fast_exp2(s0[0]), pa1 = fast_exp2(s0[1]);          \
        float pa2 = fast_exp2(s0[2]), pa3 = fast_exp2(s0[3]);          \
        float pb0 = fast_exp2(s1[0]), pb1 = fast_exp2(s1[1]);          \
        float pb2 = fast_exp2(s1[2]), pb3 = fast_exp2(s1[3]);          \
        lsum[g] += ((pa0 + pa1) + (pa2 + pa3)) + ((pb0 + pb1) + (pb2 + pb3)); \
        half4v pa = __builtin_shufflevector(pk_f16(pa0, pa1), pk_f16(pa2, pa3), 0, 1, 2, 3); \
        half4v pb = __builtin_shufflevector(pk_f16(pb0, pb1), pk_f16(pb2, pb3), 0, 1, 2, 3); \
        p8##j[g] = __builtin_shufflevector(pa, pb, 0, 1, 2, 3, 4, 5, 6, 7); \
    }                                                                  \
} while(0)

#define PV(j) do {                                                     \
    _Pragma("unroll")                                                  \
    for (int nt = 0; nt < 4; ++nt) {                                   \
        oacc[0][nt] = __builtin_amdgcn_mfma_f32_16x16x32_f16(vf##j[nt], p8##j[0], oacc[0][nt], 0, 0, 0); \
        oacc[1][nt] = __builtin_amdgcn_mfma_f32_16x16x32_f16(vf##j[nt], p8##j[1], oacc[1][nt], 0, 0, 0); \
    }                                                                  \
} while(0)

__global__ __launch_bounds__(256, 2) void attn_kernel(const f16* __restrict__ q,
                                                      const f16* __restrict__ k,
                                                      const f16* __restrict__ vt,
                                                      f16* __restrict__ ctx) {
    __shared__ f16 Klds[2][128 * 64];   // [perm-key][d] swizzled, 2 x 16 KB
    __shared__ f16 Vlds[2][64 * 128];   // [d][s] swizzled, 2 x 16 KB
    const int blk = blockIdx.x;
    const int bh = blk & 31, qt = blk >> 5;   // bh low -> XCD-local
    const int t = threadIdx.x;
    const int lane = t & 63, w = t >> 6;
    const int lr = lane & 15, quad = lane >> 4;
    const int lq7 = lr & 7;

    const f16* qbh = q + (size_t)bh * SEQ * HD;
    const f16* kbh = k + (size_t)bh * SEQ * HD;
    const f16* vbh = vt + (size_t)bh * HD * SEQ;

    const int qrow = qt * 128 + w * 32;

    const int base_k0 = lr * 64 + ((quad ^ lq7) * 8);
    const int base_k1 = lr * 64 + (((quad + 4) ^ lq7) * 8);
    int voff[4];
    #pragma unroll
    for (int g2 = 0; g2 < 4; ++g2)
        voff[g2] = lr * 128 + (((g2 * 4 + quad) ^ lr) * 8);

    auto stage = [&](f16* Kd, f16* Vd, int kt) {
        const f16* kbase = kbh + (size_t)kt * 128 * HD;
        const f16* vbase = vbh + (size_t)kt * 128;
        #pragma unroll
        for (int p = 0; p < 4; ++p) {
            int s = p * 256 + t;
            int row = s >> 3, ch = (s & 7) ^ (row & 7);
            int wk = row & 31;
            int key = (row & ~31) | ((wk & 12) << 1) | ((wk >> 4) << 2) | (wk & 3);
            cp16(&Kd[s * 8], &kbase[(size_t)key * HD + ch * 8]);
        }
        #pragma unroll
        for (int p = 0; p < 4; ++p) {
            int s = p * 256 + t;
            int row = s >> 4, ch = (s & 15) ^ (row & 15);
            cp16(&Vd[s * 8], &vbase[(size_t)row * SEQ + ch * 8]);
        }
    };

    // issue tile-0 staging first so it overlaps the Q-fragment load + scale math
    stage(Klds[0], Vlds[0], 0);

    // Q fragments pre-scaled by (1/8)*log2(e); group g covers queries qrow+g*16+lr
    half8 qf[2][2];
    #pragma unroll
    for (int g = 0; g < 2; ++g)
        #pragma unroll
        for (int ks = 0; ks < 2; ++ks) {
            half8 v = *(const half8*)(&qbh[(size_t)(qrow + g * 16 + lr) * HD + ks * 32 + quad * 8]);
            #pragma unroll
            for (int j = 0; j < 8; ++j) v[j] = (f16)((float)v[j] * 0.1803368801f);
            qf[g][ks] = v;
        }

    floatx4 oacc[2][4];
    float lsum[2] = {0.f, 0.f};
    #pragma unroll
    for (int g = 0; g < 2; ++g)
        #pragma unroll
        for (int nt4 = 0; nt4 < 4; ++nt4)
            #pragma unroll
            for (int r = 0; r < 4; ++r) oacc[g][nt4][r] = 0.f;

    // tile 0 staged by all waves before first compute
    asm volatile("s_waitcnt vmcnt(0)" ::: "memory");
    __builtin_amdgcn_s_barrier();
    asm volatile("" ::: "memory");

    for (int kt = 0; kt < 16; ++kt) {
        const int cur = kt & 1;
        // prefetch next tile into the other buffer; loads stay in flight across compute
        if (kt < 15) stage(Klds[cur ^ 1], Vlds[cur ^ 1], kt + 1);
        f16* Kl = Klds[cur];
        f16* Vl = Vlds[cur];

        half8 kf0[2][2], kf1[2][2], kf2[2][2], kf3[2][2];
        half8 vf0[4], vf1[4], vf2[4], vf3[4];
        floatx4 sc0[2][2], sc1[2][2], sc2[2][2], sc3[2][2];
        half8 p80[2], p81[2], p82[2], p83[2];

        // 1-deep software pipeline: LDS reads land under MFMAs; EXP (VALU)
        // sits between independent MFMA clusters (QK of next pair, PV of prev).
        KREAD(0); KREAD(1); VREAD(0);
        QK(0);
        KREAD(2); VREAD(1);
        QK(1);
        EXPP(0);
        KREAD(3); VREAD(2);
        QK(2);
        EXPP(1); PV(0);
        VREAD(3);
        QK(3);
        EXPP(2); PV(1);
        EXPP(3); PV(2);
        PV(3);

        // single end-of-tile sync: (a) prefetch for kt+1 landed (per-wave vmcnt + barrier),
        // (b) all waves done reading buf[cur] before kt+1 overwrites it.
        asm volatile("s_waitcnt vmcnt(0)" ::: "memory");
        __builtin_amdgcn_s_barrier();
        asm volatile("" ::: "memory");
    }

    // epilogue: reduce lsum over quad-copies, normalize, store
    const int b = bh >> 4, h = bh & 15;
    #pragma unroll
    for (int g = 0; g < 2; ++g) {
        float s = lsum[g];
        s += __shfl_xor(s, 16, 64);
        s += __shfl_xor(s, 32, 64);
        float inv = 1.f / s;
        #pragma unroll
        for (int nt4 = 0; nt4 < 4; ++nt4) {
            half4v o4;
            #pragma unroll
            for (int r = 0; r < 4; ++r) o4[r] = (f16)(oacc[g][nt4][r] * inv);
            *(half4v*)(&ctx[((size_t)(b * SEQ + qrow + g * 16 + lr)) * HIDDEN + h * HD + nt4 * 16 + quad * 4]) = o4;
        }
    }
}

#undef KREAD
#undef VREAD
#undef QK
#undef EXPP
#undef PV

// ---------------- output projection GEMM (64x128 tiles, BK=64, fp32 out) ----------------
#define OBM 64
__global__ __launch_bounds__(256, 4) void gemm_out(const f16* __restrict__ ah,
                                                   const f16* __restrict__ wto,
                                                   const float* __restrict__ bo,
                                                   float* __restrict__ out) {
    __shared__ f16 As[OBM * GBK];   // 8 KB
    __shared__ f16 Bs[BN * GBK];    // 16 KB
    const int m0 = blockIdx.y * OBM;
    const int n0 = blockIdx.x * BN;
    const int t = threadIdx.x;
    const int lane = t & 63, w = t >> 6;
    const int wm = w >> 1, wn = w & 1;   // wave tile: 32 m x 64 n
    const int lr = lane & 15, quad = lane >> 4;
    const int lq7 = lr & 7;

    const int baseA0 = wm * 2048 + lr * 64 + ((quad ^ lq7) * 8);
    const int baseA1 = wm * 2048 + lr * 64 + (((quad + 4) ^ lq7) * 8);
    const int baseB0 = wn * 4096 + lr * 64 + ((quad ^ lq7) * 8);
    const int baseB1 = wn * 4096 + lr * 64 + (((quad + 4) ^ lq7) * 8);

    floatx4 acc[2][4];
    #pragma unroll
    for (int i = 0; i < 2; ++i)
        #pragma unroll
        for (int j = 0; j < 4; ++j)
            #pragma unroll
            for (int r = 0; r < 4; ++r) acc[i][j][r] = 0.f;

    for (int k0 = 0; k0 < HIDDEN; k0 += GBK) {
        #pragma unroll
        for (int p = 0; p < 2; ++p) {
            int s = p * 256 + t;
            int row = s >> 3, ch = (s & 7) ^ (row & 7);
            cp16(&As[s * 8], &ah[(size_t)(m0 + row) * HIDDEN + k0 + ch * 8]);
        }
        #pragma unroll
        for (int p = 0; p < 4; ++p) {
            int s = p * 256 + t;
            int row = s >> 3, ch = (s & 7) ^ (row & 7);
            cp16(&Bs[s * 8], &wto[(size_t)(n0 + row) * HIDDEN + k0 + ch * 8]);
        }
        __syncthreads();
        half8 af[2], bf[4];
        #pragma unroll
        for (int i = 0; i < 2; ++i) af[i] = *(half8*)(&As[baseA0 + i * 1024]);
        #pragma unroll
        for (int j = 0; j < 4; ++j) bf[j] = *(half8*)(&Bs[baseB0 + j * 1024]);
        #pragma unroll
        for (int i = 0; i < 2; ++i)
            #pragma unroll
            for (int j = 0; j < 4; ++j)
                acc[i][j] = __builtin_amdgcn_mfma_f32_16x16x32_f16(af[i], bf[j], acc[i][j], 0, 0, 0);
        #pragma unroll
        for (int i = 0; i < 2; ++i) af[i] = *(half8*)(&As[baseA1 + i * 1024]);
        #pragma unroll
        for (int j = 0; j < 4; ++j) bf[j] = *(half8*)(&Bs[baseB1 + j * 1024]);
        #pragma unroll
        for (int i = 0; i < 2; ++i)
            #pragma unroll
            for (int j = 0; j < 4; ++j)
                acc[i][j] = __builtin_amdgcn_mfma_f32_16x16x32_f16(af[i], bf[j], acc[i][j], 0, 0, 0);
        __syncthreads();
    }

    #pragma unroll
    for (int i = 0; i < 2; ++i) {
        int mbase = m0 + wm * 32 + i * 16 + quad * 4;
        #pragma unroll
        for (int j = 0; j < 4; ++j) {
            int n = n0 + wn * 64 + j * 16 + lr;
            float bias = bo[n];
            #pragma unroll
            for (int r = 0; r < 4; ++r)
                out[(size_t)(mbase + r) * HIDDEN + n] = acc[i][j][r] + bias;
        }
    }
}

// ---------------- launch ----------------
extern "C" void kernel_launch(void* const* d_in, const int* in_sizes, int n_in,
                              void* d_out, int out_size, void* d_ws, size_t ws_size,
                              hipStream_t stream) {
    const float* x  = (const float*)d_in[0];
    const float* Wq = (const float*)d_in[1];
    const float* bq = (const float*)d_in[2];
    const float* Wk = (const float*)d_in[3];
    const float* bk = (const float*)d_in[4];
    const float* Wv = (const float*)d_in[5];
    const float* bv = (const float*)d_in[6];
    const float* Wo = (const float*)d_in[7];
    const float* bo = (const float*)d_in[8];
    float* out = (float*)d_out;

    char* ws = (char*)d_ws;
    f16* xh   = (f16*)(ws);                   // 8 MB
    f16* wt   = (f16*)(ws + (8u  << 20));     // 8 MB
    f16* qw   = (f16*)(ws + (16u << 20));     // 8 MB
    f16* kw   = (f16*)(ws + (24u << 20));     // 8 MB
    f16* vtw  = (f16*)(ws + (32u << 20));     // 8 MB (natural [d][s] layout)
    f16* ctxh = (f16*)(ws + (40u << 20));     // 8 MB

    cast_x_kernel<<<MTOT * HIDDEN / 1024, 256, 0, stream>>>(x, xh);
    castT_kernel<<<dim3(32, 32, 4), dim3(32, 32), 0, stream>>>(Wq, Wk, Wv, Wo, wt);
    gemm_qkv<<<dim3(3 * HIDDEN / BN, MTOT / BM), 256, 0, stream>>>(xh, wt, bq, bk, bv, qw, kw, vtw);
    attn_kernel<<<32 * (SEQ / 128), 256, 0, stream>>>(qw, kw, vtw, ctxh);
    gemm_out<<<dim3(HIDDEN / BN, MTOT / OBM), 256, 0, stream>>>(ctxh, wt + (size_t)3 * HIDDEN * HIDDEN, bo, out);
}